// Round 5
// baseline (2082.908 us; speedup 1.0000x reference)
//
#include <hip/hip_runtime.h>

// ---------------------------------------------------------------------------
// BiLSTM (T=784, B=512, H=200, D=1) on MI355X — round 5.
//
// Round-4 lesson: DPP row_shr reduction accumulates the row sum into the TOP
// lane (lane 15 of each 16-lane row), not lane 0 — the classic GCN pattern
// reads the LAST lane. Round 4 issued the hsum atomic from bcol==0 (which
// holds only its own value) => mean over 1/16 of the batch, absmax 2.6e-2.
// Fix: atomic from bcol==15. Everything else unchanged from round 4.
//
// Open question this round answers (no counters last round): does 1 wave/SIMD
// (__launch_bounds__(256,1), 512-reg budget) finally keep the 12 pinned
// weight tiles (336 VGPR) resident? Success indicator: VGPR_Count >= ~400.
//
// Layout:
//  * gate-interleaved M: tile mt row m -> gate q=m&3, hidden j=mt*4+(m>>2).
//  * K padded 200->224 (7 k-tiles); slots 200..204 carry the input path:
//      B[200]=1 (A=Vhi), B[201]=1 (A=Vlo), B[202]=xhi (A=Uhi),
//      B[203]=xhi (A=Ulo), B[204]=xlo (A=Uhi)
//  * h in LDS in B-fragment order, double buffered; pad rows stay 0.
//  * per block: dir = bid&1, 16-batch slice = bid>>1; 64 blocks.
//  * waves 0,1: 12 reg tiles + 1 LDS tile (mt 48 / 49); waves 2,3: 12 reg.
// ---------------------------------------------------------------------------

typedef short short8 __attribute__((ext_vector_type(8)));
typedef float f32x4 __attribute__((ext_vector_type(4)));
typedef unsigned short ushort_t;

#define T_STEPS 784
#define BATCH   512
#define HID     200
#define NKT     7     // K tiles of 32 (224 padded; slots 200..204 = input path)
#define NMT     50    // M tiles of 16 (800 rows, gate-interleaved)
#define THREADS 256   // 4 waves, 1 wave/SIMD
#define HBUF    3584  // NKT*512 ushorts per h buffer

// ws layout (bytes)
#define WS_HSUM 0                       // 784*400*4 = 1254400
#define WS_UV   1254400                 // 2*200*8*4 = 12800
#define WS_WSW  (1254400 + 12800)       // 2*50*7*512*2 = 716800

__device__ __forceinline__ ushort_t f2bf(float f) {
  union { float f; unsigned u; } x; x.f = f;
  return (ushort_t)((x.u + 0x7FFFu + ((x.u >> 16) & 1u)) >> 16);  // RNE
}
__device__ __forceinline__ float bf2f(ushort_t u) {
  union { unsigned u; float f; } x; x.u = (unsigned)u << 16; return x.f;
}

// sum over the 16 lanes of each DPP row; row_shr accumulates toward the TOP
// lane: the full row sum is valid at lane (row base + 15), i.e. bcol==15.
__device__ __forceinline__ float row16_sum(float v) {
  union { float f; int i; } a, b;
  a.f = v;
  b.i = __builtin_amdgcn_update_dpp(0, a.i, 0x118, 0xF, 0xF, true); a.f += b.f; // shr 8
  b.i = __builtin_amdgcn_update_dpp(0, a.i, 0x114, 0xF, 0xF, true); a.f += b.f; // shr 4
  b.i = __builtin_amdgcn_update_dpp(0, a.i, 0x112, 0xF, 0xF, true); a.f += b.f; // shr 2
  b.i = __builtin_amdgcn_update_dpp(0, a.i, 0x111, 0xF, 0xF, true); a.f += b.f; // shr 1
  return a.f;
}

// ---------------------------------------------------------------------------
// prep_uv: uv_g[dir][j][8] = {u_i,u_f,u_g,u_o, v_i,v_f,v_g,v_o}
// ---------------------------------------------------------------------------
__global__ void prep_uv(const float* __restrict__ Wih_f, const float* __restrict__ b_f,
                        const float* __restrict__ Wih_b, const float* __restrict__ b_b,
                        const float* __restrict__ W_in, const float* __restrict__ b_in,
                        float* __restrict__ uv_g) {
  const int dir = blockIdx.x, j = threadIdx.x;
  if (j >= HID) return;
  const float* Wih = dir ? Wih_b : Wih_f;
  const float* b   = dir ? b_b   : b_f;
  for (int q = 0; q < 4; ++q) {
    const int row = q * HID + j;
    const float* wr = Wih + (size_t)row * HID;
    float u = 0.f, v = 0.f;
    for (int k = 0; k < HID; ++k) {
      u = fmaf(wr[k], W_in[k], u);
      v = fmaf(wr[k], b_in[k], v);
    }
    uv_g[(size_t)dir * 1600 + j * 8 + q]     = u;
    uv_g[(size_t)dir * 1600 + j * 8 + 4 + q] = v + b[row];
  }
}

// ---------------------------------------------------------------------------
// prep_w: A-fragments. kt<6: Whh. kt==6: k=192..199 Whh; k=200..204 input path.
//   A-frag lane l: m=l&15 (q=m&3, j=mt*4+(m>>2)), k = kt*32+(l>>4)*8+e
// grid 700 x 64
// ---------------------------------------------------------------------------
__global__ void prep_w(const float* __restrict__ Whh_f, const float* __restrict__ Whh_b,
                       const float* __restrict__ uv_g, ushort_t* __restrict__ w_sw) {
  const int bid = blockIdx.x, lane = threadIdx.x;
  const int dir = bid / (NMT * NKT);
  const int rem = bid % (NMT * NKT);
  const int mt = rem / NKT, kt = rem % NKT;
  const float* W = dir ? Whh_b : Whh_f;
  const int m = lane & 15;
  const int q = m & 3;
  const int j = mt * 4 + (m >> 2);
  const int row = q * HID + j;
  const int grp = lane >> 4;
  short8 v8 = {0, 0, 0, 0, 0, 0, 0, 0};
  if (kt < 6) {
#pragma unroll
    for (int e = 0; e < 8; ++e)
      v8[e] = (short)f2bf(W[(size_t)row * HID + kt * 32 + grp * 8 + e]);
  } else if (grp == 0) {          // k = 192..199
#pragma unroll
    for (int e = 0; e < 8; ++e)
      v8[e] = (short)f2bf(W[(size_t)row * HID + 192 + e]);
  } else if (grp == 1) {          // k = 200..207: input-path slots
    const float U = uv_g[(size_t)dir * 1600 + j * 8 + q];
    const float V = uv_g[(size_t)dir * 1600 + j * 8 + 4 + q];
    const ushort_t vhi = f2bf(V), uhi = f2bf(U);
    v8[0] = (short)vhi;                    // * 1.0
    v8[1] = (short)f2bf(V - bf2f(vhi));    // * 1.0
    v8[2] = (short)uhi;                    // * xhi
    v8[3] = (short)f2bf(U - bf2f(uhi));    // * xhi
    v8[4] = (short)uhi;                    // * xlo
  }
  *(short8*)(w_sw + (size_t)bid * 512 + (size_t)lane * 8) = v8;
}

// ---------------------------------------------------------------------------
// per-cell LSTM update; gates (i,f,g,o) = a[0..3]. 5 exp2 + 2 rcp, clamped.
// ---------------------------------------------------------------------------
__device__ __forceinline__ void cell_update(const f32x4 a, const int haddr,
                                            ushort_t* __restrict__ hnext,
                                            float& c, float& hold) {
  const float L1 = 1.44269504088896340736f;  // log2(e)
  // clamped exp args: e <= 2^30 each, so triple product <= 2^90 (no overflow)
  const float ei = __builtin_amdgcn_exp2f(fminf(-L1 * a[0], 30.f));
  const float ef = __builtin_amdgcn_exp2f(fminf(-L1 * a[1], 30.f));
  const float eg = __builtin_amdgcn_exp2f(fminf(-2.f * L1 * a[2], 30.f));
  const float eo = __builtin_amdgcn_exp2f(fminf(-L1 * a[3], 30.f));
  const float pi = 1.f + ei, pf = 1.f + ef, pg = 1.f + eg;
  const float pig = pi * pg;
  const float R1 = __builtin_amdgcn_rcpf(pig * pf);
  const float sf = pig * R1;                    // sigmoid(f)
  const float sitg = (1.f - eg) * pf * R1;      // sigmoid(i)*tanh(g)
  const float cn = fmaf(sf, c, sitg);
  c = cn;
  // ec <= 2^83, (1+ec)(1+eo) <= 2^113: no overflow; c<-29 limit exact.
  const float ec = __builtin_amdgcn_exp2f(fminf(-2.f * L1 * cn, 83.f));
  const float R2 = __builtin_amdgcn_rcpf((1.f + ec) * (1.f + eo));
  const float h = (1.f - ec) * R2;              // sigmoid(o)*tanh(c)
  hnext[haddr] = f2bf(h);
  hold = row16_sum(h);  // batch-partial sum (valid at bcol==15)
}

// ---------------------------------------------------------------------------
// the 784-step scan. NREG reg-tiles at rbase.., NLDS (0/1) lds-tile = lbase.
// ---------------------------------------------------------------------------
template <int NREG, int NLDS>
__device__ __forceinline__ void scan_loop(
    const int rbase, const int lbase, const int dir, const int b0,
    const int lane, const int wv, const ushort_t* __restrict__ wg,
    const float* __restrict__ x, float* __restrict__ hsum,
    ushort_t* __restrict__ h_lds, const ushort_t* __restrict__ w_lds_my) {
  constexpr int NT = NREG + NLDS;
  const int bcol = lane & 15, krow = lane >> 4;
  const bool xw = (wv == 0) & (krow == 1);  // lanes 16..31 of wave 0 feed x slots

  // hoist + PIN this wave's register-resident A-fragments (non-remat'able;
  // at 1 wave/SIMD the 512-reg budget leaves no spill pressure)
  short8 wreg[NREG][NKT];
#pragma unroll
  for (int it = 0; it < NREG; ++it)
#pragma unroll
    for (int kt = 0; kt < NKT; ++kt)
      wreg[it][kt] =
          *(const short8*)(wg + ((size_t)((rbase + it) * NKT + kt)) * 512 + lane * 8);
#pragma unroll
  for (int it = 0; it < NREG; ++it)
#pragma unroll
    for (int kt = 0; kt < NKT; ++kt)
      asm volatile("" : "+v"(wreg[it][kt]));

  // per-tile h-write addresses (j = tile*4 + krow)
  int haddr[NT];
#pragma unroll
  for (int i = 0; i < NT; ++i) {
    const int tile = (i < NREG) ? rbase + i : lbase;
    const int j = tile * 4 + krow;
    haddr[i] = (j >> 5) * 512 + (bcol | (((j >> 3) & 3) << 4)) * 8 + (j & 7);
  }

  float c[NT], hold[NT];
#pragma unroll
  for (int i = 0; i < NT; ++i) { c[i] = 0.f; hold[i] = 0.f; }

  const int dcol = dir * HID;
  const int jb = rbase * 4 + krow;       // reg-tile j's are jb + 4*i
  const int jl = lbase * 4 + krow;       // lds-tile j
  int t_prev = 0, cur = 0;

  for (int s = 0; s < T_STEPS; ++s) {
    const int t = dir ? (T_STEPS - 1 - s) : s;

    // deferred hsum atomics from previous step, issued from the lane that
    // holds the row16 sum (bcol==15); drained by the NEXT barrier.
    if (s > 0 && bcol == 15) {
#pragma unroll
      for (int i = 0; i < NREG; ++i)
        atomicAdd(&hsum[(size_t)t_prev * 400 + dcol + jb + 4 * i], hold[i]);
      if constexpr (NLDS)
        atomicAdd(&hsum[(size_t)t_prev * 400 + dcol + jl], hold[NT - 1]);
    }

    // x for step s+1 (only the 16 x-writer lanes touch global x)
    const int sn = (s + 1 < T_STEPS) ? s + 1 : s;
    float xn = 0.f;
    if (xw) xn = x[(size_t)(dir ? T_STEPS - 1 - sn : sn) * BATCH + b0 + bcol];

    // B-fragments of [h(t-1); 1; x(t)]
    short8 bf[NKT];
#pragma unroll
    for (int kt = 0; kt < NKT; ++kt)
      bf[kt] = *(const short8*)&h_lds[cur * HBUF + kt * 512 + lane * 8];

    ushort_t* hnext = h_lds + (cur ^ 1) * HBUF;

    // write next step's x into hnext slots k=202..204 (e=2,3: xhi; e=4: xlo)
    if (xw) {
      const ushort_t hi = f2bf(xn);
      const ushort_t lo = f2bf(xn - bf2f(hi));
      const int sb = 6 * 512 + lane * 8;
      hnext[sb + 2] = hi;
      hnext[sb + 3] = hi;
      hnext[sb + 4] = lo;
    }

    // reg tiles in pairs (2 independent MFMA chains)
#pragma unroll
    for (int p = 0; p + 1 < NREG; p += 2) {
      f32x4 a0 = {0.f, 0.f, 0.f, 0.f}, a1 = {0.f, 0.f, 0.f, 0.f};
#pragma unroll
      for (int kt = 0; kt < NKT; ++kt) {
        a0 = __builtin_amdgcn_mfma_f32_16x16x32_bf16(wreg[p][kt],     bf[kt], a0, 0, 0, 0);
        a1 = __builtin_amdgcn_mfma_f32_16x16x32_bf16(wreg[p + 1][kt], bf[kt], a1, 0, 0, 0);
      }
      cell_update(a0, haddr[p],     hnext, c[p],     hold[p]);
      cell_update(a1, haddr[p + 1], hnext, c[p + 1], hold[p + 1]);
    }
    if constexpr (NREG & 1) {
      constexpr int p = NREG - 1;
      f32x4 a0 = {0.f, 0.f, 0.f, 0.f};
#pragma unroll
      for (int kt = 0; kt < NKT; ++kt)
        a0 = __builtin_amdgcn_mfma_f32_16x16x32_bf16(wreg[p][kt], bf[kt], a0, 0, 0, 0);
      cell_update(a0, haddr[p], hnext, c[p], hold[p]);
    }
    // LDS tile
    if constexpr (NLDS == 1) {
      f32x4 a0 = {0.f, 0.f, 0.f, 0.f};
#pragma unroll
      for (int kt = 0; kt < NKT; ++kt) {
        const short8 af = *(const short8*)&w_lds_my[kt * 512 + lane * 8];
        a0 = __builtin_amdgcn_mfma_f32_16x16x32_bf16(af, bf[kt], a0, 0, 0, 0);
      }
      cell_update(a0, haddr[NT - 1], hnext, c[NT - 1], hold[NT - 1]);
    }

    t_prev = t;
    __syncthreads();
    cur ^= 1;
  }
  if (bcol == 15) {
#pragma unroll
    for (int i = 0; i < NREG; ++i)
      atomicAdd(&hsum[(size_t)t_prev * 400 + dcol + jb + 4 * i], hold[i]);
    if constexpr (NLDS)
      atomicAdd(&hsum[(size_t)t_prev * 400 + dcol + jl], hold[NT - 1]);
  }
}

// ---------------------------------------------------------------------------
// main scan kernel: 64 blocks (dir = bid&1, slice = bid>>1), 256 threads,
// 1 wave/SIMD -> 512-VGPR budget.
// ---------------------------------------------------------------------------
__global__ __launch_bounds__(THREADS, 1) void lstm_main(
    const float* __restrict__ x, const ushort_t* __restrict__ w_sw,
    float* __restrict__ hsum) {
  __shared__ __align__(16) ushort_t h_lds[2 * HBUF];        // 14336 B
  __shared__ __align__(16) ushort_t w_lds[2 * NKT * 512];   // 14336 B

  const int tid = threadIdx.x;
  const int lane = tid & 63;
  const int wv = tid >> 6;
  const int dir = blockIdx.x & 1;
  const int b0 = (blockIdx.x >> 1) * 16;

  const ushort_t* wg = w_sw + (size_t)dir * NMT * NKT * 512;

  for (int i = tid; i < HBUF; i += THREADS) ((unsigned*)h_lds)[i] = 0;
  // stage LDS weight tiles {48,49}
  for (int i = tid; i < 2 * NKT * 64; i += THREADS) {
    const int sl = i / (NKT * 64);
    const int rem = i % (NKT * 64);
    *(short8*)&w_lds[i * 8] =
        *(const short8*)(wg + ((size_t)((48 + sl) * NKT) * 512) + rem * 8);
  }
  __syncthreads();

  // constant-1 slots (both buffers) + x(t0) slots (buffer 0)
  if (tid < 16) {
    const int t0 = dir ? T_STEPS - 1 : 0;
    const float x0 = x[(size_t)t0 * BATCH + b0 + tid];
    const ushort_t hi = f2bf(x0);
    const ushort_t lo = f2bf(x0 - bf2f(hi));
    const int sb = 6 * 512 + (16 + tid) * 8;
    h_lds[sb + 0] = 0x3F80; h_lds[sb + 1] = 0x3F80;
    h_lds[HBUF + sb + 0] = 0x3F80; h_lds[HBUF + sb + 1] = 0x3F80;
    h_lds[sb + 2] = hi; h_lds[sb + 3] = hi; h_lds[sb + 4] = lo;
  }
  __syncthreads();

  if (wv == 0) {
    scan_loop<12, 1>(0, 48, dir, b0, lane, wv, wg, x, hsum, h_lds, w_lds);
  } else if (wv == 1) {
    scan_loop<12, 1>(12, 49, dir, b0, lane, wv, wg, x, hsum, h_lds,
                     w_lds + NKT * 512);
  } else if (wv == 2) {
    scan_loop<12, 0>(24, 0, dir, b0, lane, wv, wg, x, hsum, h_lds, w_lds);
  } else {
    scan_loop<12, 0>(36, 0, dir, b0, lane, wv, wg, x, hsum, h_lds, w_lds);
  }
}

// ---------------------------------------------------------------------------
// out[t][o] = b_fc[o] + (1/512) * sum_col hsum[t][col] * W_fc[o][col]
// ---------------------------------------------------------------------------
__global__ void out_proj(const float* __restrict__ hsum, const float* __restrict__ Wfc,
                         const float* __restrict__ bfc, float* __restrict__ out) {
  const int t = blockIdx.x, tid = threadIdx.x;
  float a[10] = {0.f, 0.f, 0.f, 0.f, 0.f, 0.f, 0.f, 0.f, 0.f, 0.f};
  for (int col = tid; col < 400; col += 256) {
    const float hv = hsum[(size_t)t * 400 + col] * (1.f / 512.f);
#pragma unroll
    for (int o = 0; o < 10; ++o) a[o] = fmaf(hv, Wfc[o * 400 + col], a[o]);
  }
#pragma unroll
  for (int o = 0; o < 10; ++o) {
    float v = a[o];
    for (int m = 32; m; m >>= 1) v += __shfl_xor(v, m);
    a[o] = v;
  }
  __shared__ float red[4][10];
  if ((tid & 63) == 0)
#pragma unroll
    for (int o = 0; o < 10; ++o) red[tid >> 6][o] = a[o];
  __syncthreads();
  if (tid < 10)
    out[t * 10 + tid] = bfc[tid] + red[0][tid] + red[1][tid] + red[2][tid] + red[3][tid];
}

extern "C" void kernel_launch(void* const* d_in, const int* in_sizes, int n_in,
                              void* d_out, int out_size, void* d_ws, size_t ws_size,
                              hipStream_t stream) {
  const float* x     = (const float*)d_in[0];
  const float* W_in  = (const float*)d_in[1];
  const float* b_in  = (const float*)d_in[2];
  const float* Wih_f = (const float*)d_in[3];
  const float* Whh_f = (const float*)d_in[4];
  const float* b_f   = (const float*)d_in[5];
  const float* Wih_b = (const float*)d_in[6];
  const float* Whh_b = (const float*)d_in[7];
  const float* b_b   = (const float*)d_in[8];
  const float* W_fc  = (const float*)d_in[9];
  const float* b_fc  = (const float*)d_in[10];
  float* out = (float*)d_out;

  char* ws = (char*)d_ws;
  float*    hsum = (float*)(ws + WS_HSUM);
  float*    uv_g = (float*)(ws + WS_UV);
  ushort_t* w_sw = (ushort_t*)(ws + WS_WSW);

  hipMemsetAsync(hsum, 0, (size_t)T_STEPS * 400 * sizeof(float), stream);
  prep_uv<<<2, 256, 0, stream>>>(Wih_f, b_f, Wih_b, b_b, W_in, b_in, uv_g);
  prep_w<<<2 * NMT * NKT, 64, 0, stream>>>(Whh_f, Whh_b, uv_g, w_sw);
  lstm_main<<<64, THREADS, 0, stream>>>(x, w_sw, hsum);
  out_proj<<<T_STEPS, 256, 0, stream>>>(hsum, W_fc, b_fc, out);
}

// Round 6
// 1903.479 us; speedup vs baseline: 1.0943x; 1.0943x over previous
//
#include <hip/hip_runtime.h>

// ---------------------------------------------------------------------------
// BiLSTM (T=784, B=512, H=200, D=1) on MI355X — round 6.
//
// Round-5 lesson: "+v" pins are confined to the ARCH-VGPR class (v0..v255,
// 256 max) — the 512-reg unified file's other half is only addressable as
// AGPRs. Asking for 336 "+v" regs forced scratch spills (VGPR_Count=240,
// ~6400 cy/step of L2/scratch reloads). Fix: pin 8 tiles/wave in AGPRs
// ("+a", 224 a-regs) + 4 tiles/wave in VGPRs ("+v", 112 v-regs). gfx950 MFMA
// reads A/B straight from AGPRs (ISA §10) -> zero-copy weight residency.
// Everything else identical to round 5.
//
// Layout:
//  * gate-interleaved M: tile mt row m -> gate q=m&3, hidden j=mt*4+(m>>2).
//  * K padded 200->224 (7 k-tiles); slots 200..204 carry the input path:
//      B[200]=1 (A=Vhi), B[201]=1 (A=Vlo), B[202]=xhi (A=Uhi),
//      B[203]=xhi (A=Ulo), B[204]=xlo (A=Uhi)
//  * h in LDS in B-fragment order, double buffered; pad rows stay 0.
//  * per block: dir = bid&1, 16-batch slice = bid>>1; 64 blocks, 256 thr,
//    1 wave/SIMD (__launch_bounds__(256,1)).
//  * waves 0,1: 8a+4v reg tiles + 1 LDS tile (mt 48 / 49); waves 2,3: 8a+4v.
// ---------------------------------------------------------------------------

typedef short short8 __attribute__((ext_vector_type(8)));
typedef float f32x4 __attribute__((ext_vector_type(4)));
typedef unsigned short ushort_t;

#define T_STEPS 784
#define BATCH   512
#define HID     200
#define NKT     7     // K tiles of 32 (224 padded; slots 200..204 = input path)
#define NMT     50    // M tiles of 16 (800 rows, gate-interleaved)
#define THREADS 256   // 4 waves, 1 wave/SIMD
#define HBUF    3584  // NKT*512 ushorts per h buffer

// ws layout (bytes)
#define WS_HSUM 0                       // 784*400*4 = 1254400
#define WS_UV   1254400                 // 2*200*8*4 = 12800
#define WS_WSW  (1254400 + 12800)       // 2*50*7*512*2 = 716800

__device__ __forceinline__ ushort_t f2bf(float f) {
  union { float f; unsigned u; } x; x.f = f;
  return (ushort_t)((x.u + 0x7FFFu + ((x.u >> 16) & 1u)) >> 16);  // RNE
}
__device__ __forceinline__ float bf2f(ushort_t u) {
  union { unsigned u; float f; } x; x.u = (unsigned)u << 16; return x.f;
}

// sum over the 16 lanes of each DPP row; row_shr accumulates toward the TOP
// lane: the full row sum is valid at lane (row base + 15), i.e. bcol==15.
__device__ __forceinline__ float row16_sum(float v) {
  union { float f; int i; } a, b;
  a.f = v;
  b.i = __builtin_amdgcn_update_dpp(0, a.i, 0x118, 0xF, 0xF, true); a.f += b.f; // shr 8
  b.i = __builtin_amdgcn_update_dpp(0, a.i, 0x114, 0xF, 0xF, true); a.f += b.f; // shr 4
  b.i = __builtin_amdgcn_update_dpp(0, a.i, 0x112, 0xF, 0xF, true); a.f += b.f; // shr 2
  b.i = __builtin_amdgcn_update_dpp(0, a.i, 0x111, 0xF, 0xF, true); a.f += b.f; // shr 1
  return a.f;
}

// ---------------------------------------------------------------------------
// prep_uv: uv_g[dir][j][8] = {u_i,u_f,u_g,u_o, v_i,v_f,v_g,v_o}
// ---------------------------------------------------------------------------
__global__ void prep_uv(const float* __restrict__ Wih_f, const float* __restrict__ b_f,
                        const float* __restrict__ Wih_b, const float* __restrict__ b_b,
                        const float* __restrict__ W_in, const float* __restrict__ b_in,
                        float* __restrict__ uv_g) {
  const int dir = blockIdx.x, j = threadIdx.x;
  if (j >= HID) return;
  const float* Wih = dir ? Wih_b : Wih_f;
  const float* b   = dir ? b_b   : b_f;
  for (int q = 0; q < 4; ++q) {
    const int row = q * HID + j;
    const float* wr = Wih + (size_t)row * HID;
    float u = 0.f, v = 0.f;
    for (int k = 0; k < HID; ++k) {
      u = fmaf(wr[k], W_in[k], u);
      v = fmaf(wr[k], b_in[k], v);
    }
    uv_g[(size_t)dir * 1600 + j * 8 + q]     = u;
    uv_g[(size_t)dir * 1600 + j * 8 + 4 + q] = v + b[row];
  }
}

// ---------------------------------------------------------------------------
// prep_w: A-fragments. kt<6: Whh. kt==6: k=192..199 Whh; k=200..204 input path.
//   A-frag lane l: m=l&15 (q=m&3, j=mt*4+(m>>2)), k = kt*32+(l>>4)*8+e
// grid 700 x 64
// ---------------------------------------------------------------------------
__global__ void prep_w(const float* __restrict__ Whh_f, const float* __restrict__ Whh_b,
                       const float* __restrict__ uv_g, ushort_t* __restrict__ w_sw) {
  const int bid = blockIdx.x, lane = threadIdx.x;
  const int dir = bid / (NMT * NKT);
  const int rem = bid % (NMT * NKT);
  const int mt = rem / NKT, kt = rem % NKT;
  const float* W = dir ? Whh_b : Whh_f;
  const int m = lane & 15;
  const int q = m & 3;
  const int j = mt * 4 + (m >> 2);
  const int row = q * HID + j;
  const int grp = lane >> 4;
  short8 v8 = {0, 0, 0, 0, 0, 0, 0, 0};
  if (kt < 6) {
#pragma unroll
    for (int e = 0; e < 8; ++e)
      v8[e] = (short)f2bf(W[(size_t)row * HID + kt * 32 + grp * 8 + e]);
  } else if (grp == 0) {          // k = 192..199
#pragma unroll
    for (int e = 0; e < 8; ++e)
      v8[e] = (short)f2bf(W[(size_t)row * HID + 192 + e]);
  } else if (grp == 1) {          // k = 200..207: input-path slots
    const float U = uv_g[(size_t)dir * 1600 + j * 8 + q];
    const float V = uv_g[(size_t)dir * 1600 + j * 8 + 4 + q];
    const ushort_t vhi = f2bf(V), uhi = f2bf(U);
    v8[0] = (short)vhi;                    // * 1.0
    v8[1] = (short)f2bf(V - bf2f(vhi));    // * 1.0
    v8[2] = (short)uhi;                    // * xhi
    v8[3] = (short)f2bf(U - bf2f(uhi));    // * xhi
    v8[4] = (short)uhi;                    // * xlo
  }
  *(short8*)(w_sw + (size_t)bid * 512 + (size_t)lane * 8) = v8;
}

// ---------------------------------------------------------------------------
// per-cell LSTM update; gates (i,f,g,o) = a[0..3]. 5 exp2 + 2 rcp, clamped.
// ---------------------------------------------------------------------------
__device__ __forceinline__ void cell_update(const f32x4 a, const int haddr,
                                            ushort_t* __restrict__ hnext,
                                            float& c, float& hold) {
  const float L1 = 1.44269504088896340736f;  // log2(e)
  // clamped exp args: e <= 2^30 each, so triple product <= 2^90 (no overflow)
  const float ei = __builtin_amdgcn_exp2f(fminf(-L1 * a[0], 30.f));
  const float ef = __builtin_amdgcn_exp2f(fminf(-L1 * a[1], 30.f));
  const float eg = __builtin_amdgcn_exp2f(fminf(-2.f * L1 * a[2], 30.f));
  const float eo = __builtin_amdgcn_exp2f(fminf(-L1 * a[3], 30.f));
  const float pi = 1.f + ei, pf = 1.f + ef, pg = 1.f + eg;
  const float pig = pi * pg;
  const float R1 = __builtin_amdgcn_rcpf(pig * pf);
  const float sf = pig * R1;                    // sigmoid(f)
  const float sitg = (1.f - eg) * pf * R1;      // sigmoid(i)*tanh(g)
  const float cn = fmaf(sf, c, sitg);
  c = cn;
  // ec <= 2^83, (1+ec)(1+eo) <= 2^113: no overflow; c<-29 limit exact.
  const float ec = __builtin_amdgcn_exp2f(fminf(-2.f * L1 * cn, 83.f));
  const float R2 = __builtin_amdgcn_rcpf((1.f + ec) * (1.f + eo));
  const float h = (1.f - ec) * R2;              // sigmoid(o)*tanh(c)
  hnext[haddr] = f2bf(h);
  hold = row16_sum(h);  // batch-partial sum (valid at bcol==15)
}

// ---------------------------------------------------------------------------
// the 784-step scan. NAG AGPR-tiles + NVG VGPR-tiles at rbase..,
// NLDS (0/1) lds-tile = lbase.
// ---------------------------------------------------------------------------
template <int NAG, int NVG, int NLDS>
__device__ __forceinline__ void scan_loop(
    const int rbase, const int lbase, const int dir, const int b0,
    const int lane, const int wv, const ushort_t* __restrict__ wg,
    const float* __restrict__ x, float* __restrict__ hsum,
    ushort_t* __restrict__ h_lds, const ushort_t* __restrict__ w_lds_my) {
  constexpr int NREG = NAG + NVG;
  constexpr int NT = NREG + NLDS;
  const int bcol = lane & 15, krow = lane >> 4;
  const bool xw = (wv == 0) & (krow == 1);  // lanes 16..31 of wave 0 feed x slots

  // hoist this wave's weight fragments; pin the first NAG tiles into AGPRs
  // (a0..a255 class — MFMA reads A-operands from AGPR directly) and the next
  // NVG tiles into arch VGPRs. Pins are asm-defined => non-rematerializable.
  short8 wga[NAG][NKT];
  short8 wgv[NVG][NKT];
#pragma unroll
  for (int it = 0; it < NAG; ++it)
#pragma unroll
    for (int kt = 0; kt < NKT; ++kt)
      wga[it][kt] =
          *(const short8*)(wg + ((size_t)((rbase + it) * NKT + kt)) * 512 + lane * 8);
#pragma unroll
  for (int it = 0; it < NVG; ++it)
#pragma unroll
    for (int kt = 0; kt < NKT; ++kt)
      wgv[it][kt] = *(const short8*)(wg +
          ((size_t)((rbase + NAG + it) * NKT + kt)) * 512 + lane * 8);
#pragma unroll
  for (int it = 0; it < NAG; ++it)
#pragma unroll
    for (int kt = 0; kt < NKT; ++kt)
      asm volatile("" : "+a"(wga[it][kt]));
#pragma unroll
  for (int it = 0; it < NVG; ++it)
#pragma unroll
    for (int kt = 0; kt < NKT; ++kt)
      asm volatile("" : "+v"(wgv[it][kt]));

  // per-tile h-write addresses (j = tile*4 + krow)
  int haddr[NT];
#pragma unroll
  for (int i = 0; i < NT; ++i) {
    const int tile = (i < NREG) ? rbase + i : lbase;
    const int j = tile * 4 + krow;
    haddr[i] = (j >> 5) * 512 + (bcol | (((j >> 3) & 3) << 4)) * 8 + (j & 7);
  }

  float c[NT], hold[NT];
#pragma unroll
  for (int i = 0; i < NT; ++i) { c[i] = 0.f; hold[i] = 0.f; }

  const int dcol = dir * HID;
  const int jb = rbase * 4 + krow;       // reg-tile j's are jb + 4*i
  const int jl = lbase * 4 + krow;       // lds-tile j
  int t_prev = 0, cur = 0;

  for (int s = 0; s < T_STEPS; ++s) {
    const int t = dir ? (T_STEPS - 1 - s) : s;

    // deferred hsum atomics from previous step, issued from the lane that
    // holds the row16 sum (bcol==15); drained by the NEXT barrier.
    if (s > 0 && bcol == 15) {
#pragma unroll
      for (int i = 0; i < NREG; ++i)
        atomicAdd(&hsum[(size_t)t_prev * 400 + dcol + jb + 4 * i], hold[i]);
      if constexpr (NLDS)
        atomicAdd(&hsum[(size_t)t_prev * 400 + dcol + jl], hold[NT - 1]);
    }

    // x for step s+1 (only the 16 x-writer lanes touch global x)
    const int sn = (s + 1 < T_STEPS) ? s + 1 : s;
    float xn = 0.f;
    if (xw) xn = x[(size_t)(dir ? T_STEPS - 1 - sn : sn) * BATCH + b0 + bcol];

    // B-fragments of [h(t-1); 1; x(t)]
    short8 bf[NKT];
#pragma unroll
    for (int kt = 0; kt < NKT; ++kt)
      bf[kt] = *(const short8*)&h_lds[cur * HBUF + kt * 512 + lane * 8];

    ushort_t* hnext = h_lds + (cur ^ 1) * HBUF;

    // write next step's x into hnext slots k=202..204 (e=2,3: xhi; e=4: xlo)
    if (xw) {
      const ushort_t hi = f2bf(xn);
      const ushort_t lo = f2bf(xn - bf2f(hi));
      const int sb = 6 * 512 + lane * 8;
      hnext[sb + 2] = hi;
      hnext[sb + 3] = hi;
      hnext[sb + 4] = lo;
    }

    // AGPR tiles in pairs (2 independent MFMA chains)
#pragma unroll
    for (int p = 0; p + 1 < NAG; p += 2) {
      f32x4 a0 = {0.f, 0.f, 0.f, 0.f}, a1 = {0.f, 0.f, 0.f, 0.f};
#pragma unroll
      for (int kt = 0; kt < NKT; ++kt) {
        a0 = __builtin_amdgcn_mfma_f32_16x16x32_bf16(wga[p][kt],     bf[kt], a0, 0, 0, 0);
        a1 = __builtin_amdgcn_mfma_f32_16x16x32_bf16(wga[p + 1][kt], bf[kt], a1, 0, 0, 0);
      }
      cell_update(a0, haddr[p],     hnext, c[p],     hold[p]);
      cell_update(a1, haddr[p + 1], hnext, c[p + 1], hold[p + 1]);
    }
    // VGPR tiles in pairs
#pragma unroll
    for (int p = 0; p + 1 < NVG; p += 2) {
      const int i0 = NAG + p, i1 = NAG + p + 1;
      f32x4 a0 = {0.f, 0.f, 0.f, 0.f}, a1 = {0.f, 0.f, 0.f, 0.f};
#pragma unroll
      for (int kt = 0; kt < NKT; ++kt) {
        a0 = __builtin_amdgcn_mfma_f32_16x16x32_bf16(wgv[p][kt],     bf[kt], a0, 0, 0, 0);
        a1 = __builtin_amdgcn_mfma_f32_16x16x32_bf16(wgv[p + 1][kt], bf[kt], a1, 0, 0, 0);
      }
      cell_update(a0, haddr[i0], hnext, c[i0], hold[i0]);
      cell_update(a1, haddr[i1], hnext, c[i1], hold[i1]);
    }
    // LDS tile
    if constexpr (NLDS == 1) {
      f32x4 a0 = {0.f, 0.f, 0.f, 0.f};
#pragma unroll
      for (int kt = 0; kt < NKT; ++kt) {
        const short8 af = *(const short8*)&w_lds_my[kt * 512 + lane * 8];
        a0 = __builtin_amdgcn_mfma_f32_16x16x32_bf16(af, bf[kt], a0, 0, 0, 0);
      }
      cell_update(a0, haddr[NT - 1], hnext, c[NT - 1], hold[NT - 1]);
    }

    t_prev = t;
    __syncthreads();
    cur ^= 1;
  }
  if (bcol == 15) {
#pragma unroll
    for (int i = 0; i < NREG; ++i)
      atomicAdd(&hsum[(size_t)t_prev * 400 + dcol + jb + 4 * i], hold[i]);
    if constexpr (NLDS)
      atomicAdd(&hsum[(size_t)t_prev * 400 + dcol + jl], hold[NT - 1]);
  }
}

// ---------------------------------------------------------------------------
// main scan kernel: 64 blocks (dir = bid&1, slice = bid>>1), 256 threads,
// 1 wave/SIMD -> 256 VGPR + 256 AGPR per lane.
// ---------------------------------------------------------------------------
__global__ __launch_bounds__(THREADS, 1) void lstm_main(
    const float* __restrict__ x, const ushort_t* __restrict__ w_sw,
    float* __restrict__ hsum) {
  __shared__ __align__(16) ushort_t h_lds[2 * HBUF];        // 14336 B
  __shared__ __align__(16) ushort_t w_lds[2 * NKT * 512];   // 14336 B

  const int tid = threadIdx.x;
  const int lane = tid & 63;
  const int wv = tid >> 6;
  const int dir = blockIdx.x & 1;
  const int b0 = (blockIdx.x >> 1) * 16;

  const ushort_t* wg = w_sw + (size_t)dir * NMT * NKT * 512;

  for (int i = tid; i < HBUF; i += THREADS) ((unsigned*)h_lds)[i] = 0;
  // stage LDS weight tiles {48,49}
  for (int i = tid; i < 2 * NKT * 64; i += THREADS) {
    const int sl = i / (NKT * 64);
    const int rem = i % (NKT * 64);
    *(short8*)&w_lds[i * 8] =
        *(const short8*)(wg + ((size_t)((48 + sl) * NKT) * 512) + rem * 8);
  }
  __syncthreads();

  // constant-1 slots (both buffers) + x(t0) slots (buffer 0)
  if (tid < 16) {
    const int t0 = dir ? T_STEPS - 1 : 0;
    const float x0 = x[(size_t)t0 * BATCH + b0 + tid];
    const ushort_t hi = f2bf(x0);
    const ushort_t lo = f2bf(x0 - bf2f(hi));
    const int sb = 6 * 512 + (16 + tid) * 8;
    h_lds[sb + 0] = 0x3F80; h_lds[sb + 1] = 0x3F80;
    h_lds[HBUF + sb + 0] = 0x3F80; h_lds[HBUF + sb + 1] = 0x3F80;
    h_lds[sb + 2] = hi; h_lds[sb + 3] = hi; h_lds[sb + 4] = lo;
  }
  __syncthreads();

  if (wv == 0) {
    scan_loop<8, 4, 1>(0, 48, dir, b0, lane, wv, wg, x, hsum, h_lds, w_lds);
  } else if (wv == 1) {
    scan_loop<8, 4, 1>(12, 49, dir, b0, lane, wv, wg, x, hsum, h_lds,
                       w_lds + NKT * 512);
  } else if (wv == 2) {
    scan_loop<8, 4, 0>(24, 0, dir, b0, lane, wv, wg, x, hsum, h_lds, w_lds);
  } else {
    scan_loop<8, 4, 0>(36, 0, dir, b0, lane, wv, wg, x, hsum, h_lds, w_lds);
  }
}

// ---------------------------------------------------------------------------
// out[t][o] = b_fc[o] + (1/512) * sum_col hsum[t][col] * W_fc[o][col]
// ---------------------------------------------------------------------------
__global__ void out_proj(const float* __restrict__ hsum, const float* __restrict__ Wfc,
                         const float* __restrict__ bfc, float* __restrict__ out) {
  const int t = blockIdx.x, tid = threadIdx.x;
  float a[10] = {0.f, 0.f, 0.f, 0.f, 0.f, 0.f, 0.f, 0.f, 0.f, 0.f};
  for (int col = tid; col < 400; col += 256) {
    const float hv = hsum[(size_t)t * 400 + col] * (1.f / 512.f);
#pragma unroll
    for (int o = 0; o < 10; ++o) a[o] = fmaf(hv, Wfc[o * 400 + col], a[o]);
  }
#pragma unroll
  for (int o = 0; o < 10; ++o) {
    float v = a[o];
    for (int m = 32; m; m >>= 1) v += __shfl_xor(v, m);
    a[o] = v;
  }
  __shared__ float red[4][10];
  if ((tid & 63) == 0)
#pragma unroll
    for (int o = 0; o < 10; ++o) red[tid >> 6][o] = a[o];
  __syncthreads();
  if (tid < 10)
    out[t * 10 + tid] = bfc[tid] + red[0][tid] + red[1][tid] + red[2][tid] + red[3][tid];
}

extern "C" void kernel_launch(void* const* d_in, const int* in_sizes, int n_in,
                              void* d_out, int out_size, void* d_ws, size_t ws_size,
                              hipStream_t stream) {
  const float* x     = (const float*)d_in[0];
  const float* W_in  = (const float*)d_in[1];
  const float* b_in  = (const float*)d_in[2];
  const float* Wih_f = (const float*)d_in[3];
  const float* Whh_f = (const float*)d_in[4];
  const float* b_f   = (const float*)d_in[5];
  const float* Wih_b = (const float*)d_in[6];
  const float* Whh_b = (const float*)d_in[7];
  const float* b_b   = (const float*)d_in[8];
  const float* W_fc  = (const float*)d_in[9];
  const float* b_fc  = (const float*)d_in[10];
  float* out = (float*)d_out;

  char* ws = (char*)d_ws;
  float*    hsum = (float*)(ws + WS_HSUM);
  float*    uv_g = (float*)(ws + WS_UV);
  ushort_t* w_sw = (ushort_t*)(ws + WS_WSW);

  hipMemsetAsync(hsum, 0, (size_t)T_STEPS * 400 * sizeof(float), stream);
  prep_uv<<<2, 256, 0, stream>>>(Wih_f, b_f, Wih_b, b_b, W_in, b_in, uv_g);
  prep_w<<<2 * NMT * NKT, 64, 0, stream>>>(Whh_f, Whh_b, uv_g, w_sw);
  lstm_main<<<64, THREADS, 0, stream>>>(x, w_sw, hsum);
  out_proj<<<T_STEPS, 256, 0, stream>>>(hsum, W_fc, b_fc, out);
}

// Round 7
// 1675.279 us; speedup vs baseline: 1.2433x; 1.1362x over previous
//
#include <hip/hip_runtime.h>

// ---------------------------------------------------------------------------
// BiLSTM (T=784, B=512, H=200, D=1) on MI355X — round 7.
//
// Rounds 3/5/6 lesson: ~340 regs/lane of pinned weights is unreachable —
// the allocator spills/sinks the loads in every class mix ("+v", "+a"+"+v"),
// leaving 350KB/block/step streaming through L1 at ~56B/cy = 5400-6400
// cy/step. Fix: STRUCTURAL residency. 32 weight tiles in registers
// (4/wave x 8 waves = 112 pinned regs/wave, ask ~200 of 256) + 18 tiles in
// LDS (129KB dynamic; LDS reads bypass L1/L2 entirely). 8 waves restore
// 2-wave/SIMD issue overlap.
//
// Layout:
//  * gate-interleaved M: tile mt row m -> gate q=m&3, hidden j=mt*4+(m>>2).
//  * K padded 200->224 (7 k-tiles); slots 200..204 carry the input path:
//      B[200]=1 (A=Vhi), B[201]=1 (A=Vlo), B[202]=xhi (A=Uhi),
//      B[203]=xhi (A=Ulo), B[204]=xlo (A=Uhi)
//  * h in LDS in B-fragment order, double buffered; pad rows stay 0.
//  * per block: dir = bid&1, 16-batch slice = bid>>1; 64 blocks, 512 thr.
//  * wave w: reg tiles 4w..4w+3; LDS tiles: w<6 -> 2 (32+2w..), w>=6 -> 3.
// ---------------------------------------------------------------------------

typedef short short8 __attribute__((ext_vector_type(8)));
typedef float f32x4 __attribute__((ext_vector_type(4)));
typedef unsigned short ushort_t;

#define T_STEPS 784
#define BATCH   512
#define HID     200
#define NKT     7     // K tiles of 32 (224 padded; slots 200..204 = input path)
#define NMT     50    // M tiles of 16 (800 rows, gate-interleaved)
#define THREADS 512   // 8 waves, 2 waves/SIMD
#define HBUF    3584  // NKT*512 ushorts per h buffer
#define NLDST   18    // weight tiles resident in LDS (tiles 32..49)
#define DYN_LDS (2 * HBUF * 2 + NLDST * NKT * 512 * 2)  // 14336 + 129024 B

// ws layout (bytes)
#define WS_HSUM 0                       // 784*400*4 = 1254400
#define WS_UV   1254400                 // 2*200*8*4 = 12800
#define WS_WSW  (1254400 + 12800)       // 2*50*7*512*2 = 716800

__device__ __forceinline__ ushort_t f2bf(float f) {
  union { float f; unsigned u; } x; x.f = f;
  return (ushort_t)((x.u + 0x7FFFu + ((x.u >> 16) & 1u)) >> 16);  // RNE
}
__device__ __forceinline__ float bf2f(ushort_t u) {
  union { unsigned u; float f; } x; x.u = (unsigned)u << 16; return x.f;
}

// sum over the 16 lanes of each DPP row; row_shr accumulates toward the TOP
// lane: the full row sum is valid at lane (row base + 15), i.e. bcol==15.
__device__ __forceinline__ float row16_sum(float v) {
  union { float f; int i; } a, b;
  a.f = v;
  b.i = __builtin_amdgcn_update_dpp(0, a.i, 0x118, 0xF, 0xF, true); a.f += b.f; // shr 8
  b.i = __builtin_amdgcn_update_dpp(0, a.i, 0x114, 0xF, 0xF, true); a.f += b.f; // shr 4
  b.i = __builtin_amdgcn_update_dpp(0, a.i, 0x112, 0xF, 0xF, true); a.f += b.f; // shr 2
  b.i = __builtin_amdgcn_update_dpp(0, a.i, 0x111, 0xF, 0xF, true); a.f += b.f; // shr 1
  return a.f;
}

// ---------------------------------------------------------------------------
// prep_uv: uv_g[dir][j][8] = {u_i,u_f,u_g,u_o, v_i,v_f,v_g,v_o}
// ---------------------------------------------------------------------------
__global__ void prep_uv(const float* __restrict__ Wih_f, const float* __restrict__ b_f,
                        const float* __restrict__ Wih_b, const float* __restrict__ b_b,
                        const float* __restrict__ W_in, const float* __restrict__ b_in,
                        float* __restrict__ uv_g) {
  const int dir = blockIdx.x, j = threadIdx.x;
  if (j >= HID) return;
  const float* Wih = dir ? Wih_b : Wih_f;
  const float* b   = dir ? b_b   : b_f;
  for (int q = 0; q < 4; ++q) {
    const int row = q * HID + j;
    const float* wr = Wih + (size_t)row * HID;
    float u = 0.f, v = 0.f;
    for (int k = 0; k < HID; ++k) {
      u = fmaf(wr[k], W_in[k], u);
      v = fmaf(wr[k], b_in[k], v);
    }
    uv_g[(size_t)dir * 1600 + j * 8 + q]     = u;
    uv_g[(size_t)dir * 1600 + j * 8 + 4 + q] = v + b[row];
  }
}

// ---------------------------------------------------------------------------
// prep_w: A-fragments. kt<6: Whh. kt==6: k=192..199 Whh; k=200..204 input path.
//   A-frag lane l: m=l&15 (q=m&3, j=mt*4+(m>>2)), k = kt*32+(l>>4)*8+e
// grid 700 x 64
// ---------------------------------------------------------------------------
__global__ void prep_w(const float* __restrict__ Whh_f, const float* __restrict__ Whh_b,
                       const float* __restrict__ uv_g, ushort_t* __restrict__ w_sw) {
  const int bid = blockIdx.x, lane = threadIdx.x;
  const int dir = bid / (NMT * NKT);
  const int rem = bid % (NMT * NKT);
  const int mt = rem / NKT, kt = rem % NKT;
  const float* W = dir ? Whh_b : Whh_f;
  const int m = lane & 15;
  const int q = m & 3;
  const int j = mt * 4 + (m >> 2);
  const int row = q * HID + j;
  const int grp = lane >> 4;
  short8 v8 = {0, 0, 0, 0, 0, 0, 0, 0};
  if (kt < 6) {
#pragma unroll
    for (int e = 0; e < 8; ++e)
      v8[e] = (short)f2bf(W[(size_t)row * HID + kt * 32 + grp * 8 + e]);
  } else if (grp == 0) {          // k = 192..199
#pragma unroll
    for (int e = 0; e < 8; ++e)
      v8[e] = (short)f2bf(W[(size_t)row * HID + 192 + e]);
  } else if (grp == 1) {          // k = 200..207: input-path slots
    const float U = uv_g[(size_t)dir * 1600 + j * 8 + q];
    const float V = uv_g[(size_t)dir * 1600 + j * 8 + 4 + q];
    const ushort_t vhi = f2bf(V), uhi = f2bf(U);
    v8[0] = (short)vhi;                    // * 1.0
    v8[1] = (short)f2bf(V - bf2f(vhi));    // * 1.0
    v8[2] = (short)uhi;                    // * xhi
    v8[3] = (short)f2bf(U - bf2f(uhi));    // * xhi
    v8[4] = (short)uhi;                    // * xlo
  }
  *(short8*)(w_sw + (size_t)bid * 512 + (size_t)lane * 8) = v8;
}

// ---------------------------------------------------------------------------
// per-cell LSTM update; gates (i,f,g,o) = a[0..3]. 5 exp2 + 2 rcp, clamped.
// ---------------------------------------------------------------------------
__device__ __forceinline__ void cell_update(const f32x4 a, const int haddr,
                                            ushort_t* __restrict__ hnext,
                                            float& c, float& hold) {
  const float L1 = 1.44269504088896340736f;  // log2(e)
  // clamped exp args: e <= 2^30 each, so triple product <= 2^90 (no overflow)
  const float ei = __builtin_amdgcn_exp2f(fminf(-L1 * a[0], 30.f));
  const float ef = __builtin_amdgcn_exp2f(fminf(-L1 * a[1], 30.f));
  const float eg = __builtin_amdgcn_exp2f(fminf(-2.f * L1 * a[2], 30.f));
  const float eo = __builtin_amdgcn_exp2f(fminf(-L1 * a[3], 30.f));
  const float pi = 1.f + ei, pf = 1.f + ef, pg = 1.f + eg;
  const float pig = pi * pg;
  const float R1 = __builtin_amdgcn_rcpf(pig * pf);
  const float sf = pig * R1;                    // sigmoid(f)
  const float sitg = (1.f - eg) * pf * R1;      // sigmoid(i)*tanh(g)
  const float cn = fmaf(sf, c, sitg);
  c = cn;
  // ec <= 2^83, (1+ec)(1+eo) <= 2^113: no overflow; c<-29 limit exact.
  const float ec = __builtin_amdgcn_exp2f(fminf(-2.f * L1 * cn, 83.f));
  const float R2 = __builtin_amdgcn_rcpf((1.f + ec) * (1.f + eo));
  const float h = (1.f - ec) * R2;              // sigmoid(o)*tanh(c)
  hnext[haddr] = f2bf(h);
  hold = row16_sum(h);  // batch-partial sum (valid at bcol==15)
}

// ---------------------------------------------------------------------------
// the 784-step scan. 4 reg tiles at rbase.., NLDS LDS tiles at lfirst..
// ---------------------------------------------------------------------------
template <int NLDS>
__device__ __forceinline__ void scan_loop(
    const int rbase, const int lfirst, const int dir, const int b0,
    const int lane, const int wv, const ushort_t* __restrict__ wg,
    const float* __restrict__ x, float* __restrict__ hsum,
    ushort_t* __restrict__ h_lds, const ushort_t* __restrict__ w_lds_my) {
  constexpr int NREG = 4;
  constexpr int NT = NREG + NLDS;
  const int bcol = lane & 15, krow = lane >> 4;
  const bool xw = (wv == 0) & (krow == 1);  // lanes 16..31 of wave 0 feed x slots

  // hoist + pin this wave's 4 register tiles (112 VGPRs; ask ~200 of 256)
  short8 wreg[NREG][NKT];
#pragma unroll
  for (int it = 0; it < NREG; ++it)
#pragma unroll
    for (int kt = 0; kt < NKT; ++kt)
      wreg[it][kt] =
          *(const short8*)(wg + ((size_t)((rbase + it) * NKT + kt)) * 512 + lane * 8);
#pragma unroll
  for (int it = 0; it < NREG; ++it)
#pragma unroll
    for (int kt = 0; kt < NKT; ++kt)
      asm volatile("" : "+v"(wreg[it][kt]));

  // per-tile h-write addresses (j = tile*4 + krow)
  int haddr[NT];
#pragma unroll
  for (int i = 0; i < NT; ++i) {
    const int tile = (i < NREG) ? rbase + i : lfirst + (i - NREG);
    const int j = tile * 4 + krow;
    haddr[i] = (j >> 5) * 512 + (bcol | (((j >> 3) & 3) << 4)) * 8 + (j & 7);
  }

  float c[NT], hold[NT];
#pragma unroll
  for (int i = 0; i < NT; ++i) { c[i] = 0.f; hold[i] = 0.f; }

  const int dcol = dir * HID;
  const int jb = rbase * 4 + krow;       // reg-tile j's are jb + 4*i
  const int jl = lfirst * 4 + krow;      // lds-tile j's are jl + 4*i
  int t_prev = 0, cur = 0;

  for (int s = 0; s < T_STEPS; ++s) {
    const int t = dir ? (T_STEPS - 1 - s) : s;

    // deferred hsum atomics from previous step, issued from the lane that
    // holds the row16 sum (bcol==15); drained by the NEXT barrier.
    if (s > 0 && bcol == 15) {
#pragma unroll
      for (int i = 0; i < NREG; ++i)
        atomicAdd(&hsum[(size_t)t_prev * 400 + dcol + jb + 4 * i], hold[i]);
#pragma unroll
      for (int i = 0; i < NLDS; ++i)
        atomicAdd(&hsum[(size_t)t_prev * 400 + dcol + jl + 4 * i], hold[NREG + i]);
    }

    // x for step s+1 (only the 16 x-writer lanes touch global x)
    const int sn = (s + 1 < T_STEPS) ? s + 1 : s;
    float xn = 0.f;
    if (xw) xn = x[(size_t)(dir ? T_STEPS - 1 - sn : sn) * BATCH + b0 + bcol];

    // B-fragments of [h(t-1); 1; x(t)]
    short8 bf[NKT];
#pragma unroll
    for (int kt = 0; kt < NKT; ++kt)
      bf[kt] = *(const short8*)&h_lds[cur * HBUF + kt * 512 + lane * 8];

    ushort_t* hnext = h_lds + (cur ^ 1) * HBUF;

    // write next step's x into hnext slots k=202..204 (e=2,3: xhi; e=4: xlo)
    if (xw) {
      const ushort_t hi = f2bf(xn);
      const ushort_t lo = f2bf(xn - bf2f(hi));
      const int sb = 6 * 512 + lane * 8;
      hnext[sb + 2] = hi;
      hnext[sb + 3] = hi;
      hnext[sb + 4] = lo;
    }

    // reg tiles in pairs (2 independent MFMA chains)
#pragma unroll
    for (int p = 0; p + 1 < NREG; p += 2) {
      f32x4 a0 = {0.f, 0.f, 0.f, 0.f}, a1 = {0.f, 0.f, 0.f, 0.f};
#pragma unroll
      for (int kt = 0; kt < NKT; ++kt) {
        a0 = __builtin_amdgcn_mfma_f32_16x16x32_bf16(wreg[p][kt],     bf[kt], a0, 0, 0, 0);
        a1 = __builtin_amdgcn_mfma_f32_16x16x32_bf16(wreg[p + 1][kt], bf[kt], a1, 0, 0, 0);
      }
      cell_update(a0, haddr[p],     hnext, c[p],     hold[p]);
      cell_update(a1, haddr[p + 1], hnext, c[p + 1], hold[p + 1]);
    }
    // LDS tiles in pairs (+ tail single when NLDS is odd)
#pragma unroll
    for (int p = 0; p + 1 < NLDS; p += 2) {
      const int i0 = NREG + p, i1 = NREG + p + 1;
      f32x4 a0 = {0.f, 0.f, 0.f, 0.f}, a1 = {0.f, 0.f, 0.f, 0.f};
#pragma unroll
      for (int kt = 0; kt < NKT; ++kt) {
        const short8 af0 = *(const short8*)&w_lds_my[((p)     * NKT + kt) * 512 + lane * 8];
        const short8 af1 = *(const short8*)&w_lds_my[((p + 1) * NKT + kt) * 512 + lane * 8];
        a0 = __builtin_amdgcn_mfma_f32_16x16x32_bf16(af0, bf[kt], a0, 0, 0, 0);
        a1 = __builtin_amdgcn_mfma_f32_16x16x32_bf16(af1, bf[kt], a1, 0, 0, 0);
      }
      cell_update(a0, haddr[i0], hnext, c[i0], hold[i0]);
      cell_update(a1, haddr[i1], hnext, c[i1], hold[i1]);
    }
    if constexpr (NLDS & 1) {
      constexpr int p = NLDS - 1;
      const int i0 = NREG + p;
      f32x4 a0 = {0.f, 0.f, 0.f, 0.f};
#pragma unroll
      for (int kt = 0; kt < NKT; ++kt) {
        const short8 af = *(const short8*)&w_lds_my[(p * NKT + kt) * 512 + lane * 8];
        a0 = __builtin_amdgcn_mfma_f32_16x16x32_bf16(af, bf[kt], a0, 0, 0, 0);
      }
      cell_update(a0, haddr[i0], hnext, c[i0], hold[i0]);
    }

    t_prev = t;
    __syncthreads();
    cur ^= 1;
  }
  if (bcol == 15) {
#pragma unroll
    for (int i = 0; i < NREG; ++i)
      atomicAdd(&hsum[(size_t)t_prev * 400 + dcol + jb + 4 * i], hold[i]);
#pragma unroll
    for (int i = 0; i < NLDS; ++i)
      atomicAdd(&hsum[(size_t)t_prev * 400 + dcol + jl + 4 * i], hold[NREG + i]);
  }
}

// ---------------------------------------------------------------------------
// main scan kernel: 64 blocks (dir = bid&1, slice = bid>>1), 512 threads.
// Dynamic LDS: h dbuf (14336 B) + 18 weight tiles (129024 B) = 143360 B.
// ---------------------------------------------------------------------------
__global__ __launch_bounds__(THREADS) void lstm_main(
    const float* __restrict__ x, const ushort_t* __restrict__ w_sw,
    float* __restrict__ hsum) {
  extern __shared__ __align__(16) ushort_t dynlds[];
  ushort_t* h_lds = dynlds;                  // 2*HBUF ushorts
  ushort_t* w_lds = dynlds + 2 * HBUF;       // NLDST*NKT*512 ushorts

  const int tid = threadIdx.x;
  const int lane = tid & 63;
  const int wv = tid >> 6;
  const int dir = blockIdx.x & 1;
  const int b0 = (blockIdx.x >> 1) * 16;

  const ushort_t* wg = w_sw + (size_t)dir * NMT * NKT * 512;

  for (int i = tid; i < HBUF; i += THREADS) ((unsigned*)h_lds)[i] = 0;
  // stage LDS weight tiles 32..49 (contiguous block in w_sw)
  for (int i = tid; i < NLDST * NKT * 64; i += THREADS)
    *(short8*)&w_lds[(size_t)i * 8] =
        *(const short8*)(wg + (size_t)32 * NKT * 512 + (size_t)i * 8);
  __syncthreads();

  // constant-1 slots (both buffers) + x(t0) slots (buffer 0)
  if (tid < 16) {
    const int t0 = dir ? T_STEPS - 1 : 0;
    const float x0 = x[(size_t)t0 * BATCH + b0 + tid];
    const ushort_t hi = f2bf(x0);
    const ushort_t lo = f2bf(x0 - bf2f(hi));
    const int sb = 6 * 512 + (16 + tid) * 8;
    h_lds[sb + 0] = 0x3F80; h_lds[sb + 1] = 0x3F80;
    h_lds[HBUF + sb + 0] = 0x3F80; h_lds[HBUF + sb + 1] = 0x3F80;
    h_lds[sb + 2] = hi; h_lds[sb + 3] = hi; h_lds[sb + 4] = lo;
  }
  __syncthreads();

  // wave w: reg tiles 4w..4w+3; LDS tiles: w<6 -> {32+2w, +1}, w>=6 -> 3 tiles
  const int rbase = 4 * wv;
  const int lfirst = (wv < 6) ? (32 + 2 * wv) : (44 + 3 * (wv - 6));
  const ushort_t* wl = w_lds + (size_t)(lfirst - 32) * NKT * 512;
  if (wv < 6)
    scan_loop<2>(rbase, lfirst, dir, b0, lane, wv, wg, x, hsum, h_lds, wl);
  else
    scan_loop<3>(rbase, lfirst, dir, b0, lane, wv, wg, x, hsum, h_lds, wl);
}

// ---------------------------------------------------------------------------
// out[t][o] = b_fc[o] + (1/512) * sum_col hsum[t][col] * W_fc[o][col]
// ---------------------------------------------------------------------------
__global__ void out_proj(const float* __restrict__ hsum, const float* __restrict__ Wfc,
                         const float* __restrict__ bfc, float* __restrict__ out) {
  const int t = blockIdx.x, tid = threadIdx.x;
  float a[10] = {0.f, 0.f, 0.f, 0.f, 0.f, 0.f, 0.f, 0.f, 0.f, 0.f};
  for (int col = tid; col < 400; col += 256) {
    const float hv = hsum[(size_t)t * 400 + col] * (1.f / 512.f);
#pragma unroll
    for (int o = 0; o < 10; ++o) a[o] = fmaf(hv, Wfc[o * 400 + col], a[o]);
  }
#pragma unroll
  for (int o = 0; o < 10; ++o) {
    float v = a[o];
    for (int m = 32; m; m >>= 1) v += __shfl_xor(v, m);
    a[o] = v;
  }
  __shared__ float red[4][10];
  if ((tid & 63) == 0)
#pragma unroll
    for (int o = 0; o < 10; ++o) red[tid >> 6][o] = a[o];
  __syncthreads();
  if (tid < 10)
    out[t * 10 + tid] = bfc[tid] + red[0][tid] + red[1][tid] + red[2][tid] + red[3][tid];
}

extern "C" void kernel_launch(void* const* d_in, const int* in_sizes, int n_in,
                              void* d_out, int out_size, void* d_ws, size_t ws_size,
                              hipStream_t stream) {
  const float* x     = (const float*)d_in[0];
  const float* W_in  = (const float*)d_in[1];
  const float* b_in  = (const float*)d_in[2];
  const float* Wih_f = (const float*)d_in[3];
  const float* Whh_f = (const float*)d_in[4];
  const float* b_f   = (const float*)d_in[5];
  const float* Wih_b = (const float*)d_in[6];
  const float* Whh_b = (const float*)d_in[7];
  const float* b_b   = (const float*)d_in[8];
  const float* W_fc  = (const float*)d_in[9];
  const float* b_fc  = (const float*)d_in[10];
  float* out = (float*)d_out;

  char* ws = (char*)d_ws;
  float*    hsum = (float*)(ws + WS_HSUM);
  float*    uv_g = (float*)(ws + WS_UV);
  ushort_t* w_sw = (ushort_t*)(ws + WS_WSW);

  // opt-in to >64KB dynamic LDS (host-side attribute; not a stream op, safe
  // under graph capture; idempotent and deterministic)
  hipFuncSetAttribute((const void*)lstm_main,
                      hipFuncAttributeMaxDynamicSharedMemorySize, DYN_LDS);

  hipMemsetAsync(hsum, 0, (size_t)T_STEPS * 400 * sizeof(float), stream);
  prep_uv<<<2, 256, 0, stream>>>(Wih_f, b_f, Wih_b, b_b, W_in, b_in, uv_g);
  prep_w<<<2 * NMT * NKT, 64, 0, stream>>>(Whh_f, Whh_b, uv_g, w_sw);
  lstm_main<<<64, THREADS, DYN_LDS, stream>>>(x, w_sw, hsum);
  out_proj<<<T_STEPS, 256, 0, stream>>>(hsum, W_fc, b_fc, out);
}